// Round 6
// baseline (1585.278 us; speedup 1.0000x reference)
//
#include <hip/hip_runtime.h>
#include <hip/hip_cooperative_groups.h>
#include <cstdint>

namespace cg = cooperative_groups;

#define N_NODES 50000
#define N_EDGES 800000
#define HDIM    128
#define TIE_CAP 44000
#define NITER   2

typedef __attribute__((ext_vector_type(8))) short bf16x8;
typedef __attribute__((ext_vector_type(4))) float f32x4;

struct Params {
    const float *h, *e, *attr;
    const float *W_er1, *b_er1, *W_er2, *b_er2;
    const float *W_ih, *W_hh, *b_ih, *b_hh;
    const float *W_nn, *b_nn, *W_g1, *b_g1, *W_g2, *b_g2;
    const int* ei; const void* tie_raw;
    float *out_h, *out_e;
    float *cpl_cnt, *w_den, *deg_inv, *sumw, *w_arr, *m_edge, *csr_w;
    int *hist, *counters, *tie_list, *tie_row, *tie_col;
    int *excl, *bsum, *row_ptr, *cursor, *csr_row;
    short *BTer1, *BTer2, *BTnn, *BTg1, *BTcomb, *BTihn, *BThhn;
    uint16_t *h_bf, *agg;
};

__device__ __forceinline__ uint32_t f2bf(float f) {
    uint32_t u = __builtin_bit_cast(uint32_t, f);
    return (u + 0x7fffu + ((u >> 16) & 1u)) >> 16;   // RNE
}
__device__ __forceinline__ float bf2f(uint32_t b) {
    return __builtin_bit_cast(float, b << 16);
}
__device__ __forceinline__ uint32_t comb2(uint32_t me, uint32_t mn, float g) {
    float a0 = bf2f(me & 0xffffu) + g * bf2f(mn & 0xffffu);
    float a1 = bf2f(me >> 16)     + g * bf2f(mn >> 16);
    return f2bf(a0) | (f2bf(a1) << 16);
}

// ---- LDS tiles: [128 rows][128 bf16] = 256B rows, byte ^= (row&7)<<4 ----
__device__ __forceinline__ void stage_a128(const float* __restrict__ base,
                                           const int* __restrict__ gidx,
                                           int m0, int Mlim, char* tile, int tid)
{
    const int c = tid & 15;
    #pragma unroll
    for (int p = 0; p < 4; ++p) {
        int row = p * 32 + (tid >> 4);
        int ar = m0 + row; if (ar >= Mlim) ar = Mlim - 1;
        long g = gidx ? gidx[ar] : ar;
        const float* s = base + g * HDIM + c * 4;
        float4 v0 = *(const float4*)s;
        float4 v1 = *(const float4*)(s + 64);
        uint2 w0 = make_uint2(f2bf(v0.x) | (f2bf(v0.y) << 16),
                              f2bf(v0.z) | (f2bf(v0.w) << 16));
        uint2 w1 = make_uint2(f2bf(v1.x) | (f2bf(v1.y) << 16),
                              f2bf(v1.z) | (f2bf(v1.w) << 16));
        int sw = (row & 7) << 4;
        *(uint2*)(tile + row * 256 + ((c * 8) ^ sw)) = w0;
        *(uint2*)(tile + row * 256 + ((c * 8 + 128) ^ sw)) = w1;
    }
}

__device__ __forceinline__ void stage_bf128(const uint16_t* __restrict__ base,
                                            const int* __restrict__ gidx,
                                            int m0, int Mlim, char* tile, int tid)
{
    const int c = tid & 15;
    #pragma unroll
    for (int p = 0; p < 4; ++p) {
        int row = p * 32 + (tid >> 4);
        int ar = m0 + row; if (ar >= Mlim) ar = Mlim - 1;
        long g = gidx ? gidx[ar] : ar;
        uint4 v = *(const uint4*)(base + g * HDIM + c * 8);
        *(uint4*)(tile + row * 256 + ((c * 16) ^ ((row & 7) << 4))) = v;
    }
}

__device__ __forceinline__ void stage_b128(const short* __restrict__ BT, int ldk,
                                           int n0, int k0, char* tile, int tid)
{
    const int c = tid & 15;
    #pragma unroll
    for (int p = 0; p < 4; ++p) {
        int n = p * 32 + (tid >> 4);
        uint4 v = *(const uint4*)&BT[(size_t)(n0 + n) * ldk + k0 + c * 8];
        *(uint4*)(tile + n * 256 + ((c * 16) ^ ((n & 7) << 4))) = v;
    }
}

__device__ __forceinline__ void mfma128(const char* At, const char* Bt,
                                        int wr, int wc, int lane, f32x4 acc[4][2])
{
    #pragma unroll
    for (int ks = 0; ks < 4; ++ks) {
        int kb = ks * 64 + (lane >> 4) * 16;
        bf16x8 aF[4], bF[2];
        #pragma unroll
        for (int mi = 0; mi < 4; ++mi) {
            int row = wr * 64 + mi * 16 + (lane & 15);
            aF[mi] = *(const bf16x8*)(At + row * 256 + (kb ^ ((row & 7) << 4)));
        }
        #pragma unroll
        for (int ni = 0; ni < 2; ++ni) {
            int n = wc * 32 + ni * 16 + (lane & 15);
            bF[ni] = *(const bf16x8*)(Bt + n * 256 + (kb ^ ((n & 7) << 4)));
        }
        #pragma unroll
        for (int mi = 0; mi < 4; ++mi)
            #pragma unroll
            for (int ni = 0; ni < 2; ++ni)
                acc[mi][ni] = __builtin_amdgcn_mfma_f32_16x16x32_bf16(
                    aF[mi], bF[ni], acc[mi][ni], 0, 0, 0);
    }
}

// ---------------- tie tile: L1 -> relu -> L2 -> e upd + m_edge scatter ------
__device__ __forceinline__ void tie_tile(const Params& P, int m0, int cnt,
                                         char* At, char* B0, char* B1,
                                         int tid, int lane, int wr, int wc)
{
    f32x4 acc0[4][2] = {}, acc1[4][2] = {};
    #pragma unroll 1
    for (int c = 0; c < 3; ++c) {
        if (c == 0) stage_a128(P.out_e, P.tie_list, m0, cnt, At, tid);
        else        stage_bf128(P.h_bf, (c == 1) ? P.tie_row : P.tie_col, m0, cnt, At, tid);
        stage_b128(P.BTer1, 384, 0,   c * 128, B0, tid);
        stage_b128(P.BTer1, 384, 128, c * 128, B1, tid);
        __syncthreads();
        mfma128(At, B0, wr, wc, lane, acc0);
        mfma128(At, B1, wr, wc, lane, acc1);
        __syncthreads();
    }
    #pragma unroll
    for (int half = 0; half < 2; ++half) {
        char* Ct = half ? B0 : At;
        #pragma unroll
        for (int ni = 0; ni < 2; ++ni) {
            int col = wc * 32 + ni * 16 + (lane & 15);
            float bv = P.b_er1[half * 128 + col];
            #pragma unroll
            for (int mi = 0; mi < 4; ++mi)
                #pragma unroll
                for (int j = 0; j < 4; ++j) {
                    int rl = wr * 64 + mi * 16 + ((lane >> 4) << 2) + j;
                    float v = fmaxf((half ? acc1 : acc0)[mi][ni][j] + bv, 0.f);
                    *(uint16_t*)(Ct + rl * 256 + ((col * 2) ^ ((rl & 7) << 4))) =
                        (uint16_t)f2bf(v);
                }
        }
    }
    stage_b128(P.BTer2, 256, 0, 0, B1, tid);
    __syncthreads();
    f32x4 acc2[4][2] = {};
    mfma128(At, B1, wr, wc, lane, acc2);
    __syncthreads();
    stage_b128(P.BTer2, 256, 0, 128, B1, tid);
    __syncthreads();
    mfma128(B0, B1, wr, wc, lane, acc2);

    int col0 = wc * 32 + (lane & 15);
    float bv0 = P.b_er2[col0], bv1 = P.b_er2[col0 + 16];
    #pragma unroll
    for (int mi = 0; mi < 4; ++mi) {
        #pragma unroll
        for (int j = 0; j < 4; ++j) {
            int i = m0 + wr * 64 + mi * 16 + ((lane >> 4) << 2) + j;
            if (i < cnt) {
                int e = P.tie_list[i], r = P.tie_row[i], cc = P.tie_col[i];
                float dr = P.deg_inv[r], dc = P.deg_inv[cc];
                #pragma unroll
                for (int ni = 0; ni < 2; ++ni) {
                    int col = col0 + ni * 16;
                    float er = acc2[mi][ni][j] + (ni ? bv1 : bv0);
                    size_t eb = (size_t)e * HDIM + col;
                    float v = P.out_e[eb] + er;
                    P.out_e[eb] = v;
                    atomicAdd(&P.m_edge[(size_t)r * HDIM + col], v * dr);
                    atomicAdd(&P.m_edge[(size_t)cc * HDIM + col], v * dc);
                }
            }
        }
    }
}

// ---------------- mega tile: m_node GEMM + gate + GRU (+ m_edge self-zero) --
__device__ __forceinline__ void mega_tile(const Params& P, int m0,
                                          char* Tme, char* Tmn, char* Th, char* Bt,
                                          float (&g_red)[4][128], float* g_fin,
                                          float* sw_s,
                                          int tid, int lane, int wr, int wc)
{
    stage_a128(P.m_edge, nullptr, m0, N_NODES, Tme, tid);
    stage_bf128(P.agg,   nullptr, m0, N_NODES, Tmn, tid);
    stage_bf128(P.h_bf,  nullptr, m0, N_NODES, Th,  tid);
    stage_b128(P.BTnn, 128, 0, 0, Bt, tid);
    if (tid < 128) {
        int n = m0 + tid; if (n >= N_NODES) n = N_NODES - 1;
        sw_s[tid] = P.sumw[n];
    }
    __syncthreads();

    // zero own m_edge rows (tiles partition nodes; safe vs other blocks)
    {
        int lim = (N_NODES - m0 < 128 ? N_NODES - m0 : 128) * HDIM / 4;
        float4* mp = (float4*)(P.m_edge + (size_t)m0 * HDIM);
        for (int i = tid; i < lim; i += 512) mp[i] = make_float4(0.f, 0.f, 0.f, 0.f);
    }

    // phase 0: m_node = agg @ W_nn + sumw*b_nn -> bf16 into Tmn
    {
        f32x4 accM[4][2] = {};
        mfma128(Tmn, Bt, wr, wc, lane, accM);
        __syncthreads();
        #pragma unroll
        for (int ni = 0; ni < 2; ++ni) {
            int col = wc * 32 + ni * 16 + (lane & 15);
            float bv = P.b_nn[col];
            #pragma unroll
            for (int mi = 0; mi < 4; ++mi)
                #pragma unroll
                for (int j = 0; j < 4; ++j) {
                    int rl = wr * 64 + mi * 16 + ((lane >> 4) << 2) + j;
                    float v = accM[mi][ni][j] + sw_s[rl] * bv;
                    *(uint16_t*)(Tmn + rl * 256 + ((col * 2) ^ ((rl & 7) << 4))) =
                        (uint16_t)f2bf(v);
                }
        }
        __syncthreads();
    }

    // gate GEMM: [me|mn|h](K=384) @ W_g1
    f32x4 accG[4][2] = {};
    #pragma unroll 1
    for (int c = 0; c < 3; ++c) {
        const char* Ac = (c == 0) ? Tme : (c == 1) ? Tmn : Th;
        stage_b128(P.BTg1, 384, 0, c * 128, Bt, tid);
        __syncthreads();
        mfma128(Ac, Bt, wr, wc, lane, accG);
        __syncthreads();
    }
    {
        float bg[2], wg[2];
        #pragma unroll
        for (int ni = 0; ni < 2; ++ni) {
            int col = wc * 32 + ni * 16 + (lane & 15);
            bg[ni] = P.b_g1[col]; wg[ni] = P.W_g2[col];
        }
        #pragma unroll
        for (int mi = 0; mi < 4; ++mi)
            #pragma unroll
            for (int j = 0; j < 4; ++j) {
                float p = fmaxf(accG[mi][0][j] + bg[0], 0.f) * wg[0]
                        + fmaxf(accG[mi][1][j] + bg[1], 0.f) * wg[1];
                #pragma unroll
                for (int o = 8; o; o >>= 1) p += __shfl_xor(p, o);
                if ((lane & 15) == 0)
                    g_red[wc][wr * 64 + mi * 16 + ((lane >> 4) << 2) + j] = p;
            }
    }
    __syncthreads();
    if (tid < 128) {
        float t = g_red[0][tid] + g_red[1][tid] + g_red[2][tid] + g_red[3][tid]
                + P.b_g2[0];
        g_fin[tid] = 1.f / (1.f + __expf(-t));
    }
    __syncthreads();

    // M = me + g*mn (bf16, in place of Tmn)
    {
        const int c = tid & 15;
        #pragma unroll
        for (int p = 0; p < 4; ++p) {
            int row = p * 32 + (tid >> 4);
            float g = g_fin[row];
            int sw = (row & 7) << 4;
            #pragma unroll
            for (int hh = 0; hh < 2; ++hh) {
                int off = (c * 8 + hh * 128) ^ sw;
                uint2 me2 = *(uint2*)(Tme + row * 256 + off);
                uint2 mn2 = *(uint2*)(Tmn + row * 256 + off);
                uint2 o2 = make_uint2(comb2(me2.x, mn2.x, g), comb2(me2.y, mn2.y, g));
                *(uint2*)(Tmn + row * 256 + off) = o2;
            }
        }
    }
    __syncthreads();

    // GRU phases
    f32x4 aR[4][2] = {}, aZ[4][2] = {}, aGI[4][2] = {}, aGH[4][2] = {};
    stage_b128(P.BTcomb, 256, 0, 0, Bt, tid);     __syncthreads();
    mfma128(Tmn, Bt, wr, wc, lane, aR);           __syncthreads();
    stage_b128(P.BTcomb, 256, 0, 128, Bt, tid);   __syncthreads();
    mfma128(Th, Bt, wr, wc, lane, aR);            __syncthreads();
    stage_b128(P.BTcomb, 256, 128, 0, Bt, tid);   __syncthreads();
    mfma128(Tmn, Bt, wr, wc, lane, aZ);           __syncthreads();
    stage_b128(P.BTcomb, 256, 128, 128, Bt, tid); __syncthreads();
    mfma128(Th, Bt, wr, wc, lane, aZ);            __syncthreads();
    stage_b128(P.BTihn, 128, 0, 0, Bt, tid);      __syncthreads();
    mfma128(Tmn, Bt, wr, wc, lane, aGI);          __syncthreads();
    stage_b128(P.BThhn, 128, 0, 0, Bt, tid);      __syncthreads();
    mfma128(Th, Bt, wr, wc, lane, aGH);

    // GRU epilogue (masked to coupling buses); maintains h_bf shadow
    #pragma unroll
    for (int ni = 0; ni < 2; ++ni) {
        int col = wc * 32 + ni * 16 + (lane & 15);
        float br  = P.b_ih[col] + P.b_hh[col];
        float bz  = P.b_ih[128 + col] + P.b_hh[128 + col];
        float bin = P.b_ih[256 + col], bhn = P.b_hh[256 + col];
        #pragma unroll
        for (int mi = 0; mi < 4; ++mi)
            #pragma unroll
            for (int j = 0; j < 4; ++j) {
                int node = m0 + wr * 64 + mi * 16 + ((lane >> 4) << 2) + j;
                if (node < N_NODES && P.cpl_cnt[node] > 0.f) {
                    float r = 1.f / (1.f + __expf(-(aR[mi][ni][j] + br)));
                    float z = 1.f / (1.f + __expf(-(aZ[mi][ni][j] + bz)));
                    float nn = tanhf(aGI[mi][ni][j] + bin + r * (aGH[mi][ni][j] + bhn));
                    size_t hb = (size_t)node * HDIM + col;
                    float hv = P.out_h[hb];
                    float hn = (1.f - z) * nn + z * hv;
                    P.out_h[hb] = hn;
                    P.h_bf[hb] = (uint16_t)f2bf(hn);
                }
            }
    }
}

// ---------------- the single cooperative kernel ----------------
__global__ __launch_bounds__(512)
void k_mono(Params P)
{
    cg::grid_group grid = cg::this_grid();
    __shared__ __align__(16) char S0[32 * 1024];
    __shared__ __align__(16) char S1[32 * 1024];
    __shared__ __align__(16) char S2[32 * 1024];
    __shared__ __align__(16) char S3[32 * 1024];
    __shared__ float g_red[4][128];
    __shared__ float g_fin[128];
    __shared__ float sw_s[128];
    __shared__ int   scan_s[512];

    const int tid = threadIdx.x, bid = blockIdx.x;
    const int lane = tid & 63, wid = tid >> 6, wr = wid >> 2, wc = wid & 3;
    const int nb = gridDim.x;
    const int gtid = bid * 512 + tid, gstr = nb * 512;

    // ---- P0: detect + copies + zeroing + weight prep ----
    if (bid == 0 && tid < 64) {
        const uint8_t* tr = (const uint8_t*)P.tie_raw;
        int c = 0;
        for (int i = tid; i < 4096; i += 64)
            if ((i & 3) && tr[i]) c = 1;
        unsigned long long m = __ballot(c != 0);
        if (tid == 0) { P.counters[0] = (m != 0ull) ? 1 : 0; P.counters[1] = 0; P.counters[2] = 0; }
    }
    for (int i = gtid; i < N_NODES * HDIM / 4; i += gstr) {
        float4 v = ((const float4*)P.h)[i];
        ((float4*)P.out_h)[i] = v;
        uint2 w = make_uint2(f2bf(v.x) | (f2bf(v.y) << 16),
                             f2bf(v.z) | (f2bf(v.w) << 16));
        *(uint2*)(P.h_bf + (size_t)i * 4) = w;
    }
    for (int i = gtid; i < N_EDGES * HDIM / 4; i += gstr)
        ((float4*)P.out_e)[i] = ((const float4*)P.e)[i];
    for (int i = gtid; i < N_NODES; i += gstr) {
        P.cpl_cnt[i] = 0.f; P.w_den[i] = 0.f; P.hist[i] = 0;
    }
    for (int i = gtid; i < N_NODES * HDIM / 4; i += gstr)
        ((float4*)P.m_edge)[i] = make_float4(0.f, 0.f, 0.f, 0.f);
    for (int i = gtid; i < 384 * 256; i += gstr) { int n = i / 384, k = i % 384; P.BTer1[i] = (short)f2bf(P.W_er1[(size_t)k * 256 + n]); }
    for (int i = gtid; i < 128 * 256; i += gstr) { int n = i / 256, k = i % 256; P.BTer2[i] = (short)f2bf(P.W_er2[(size_t)k * 128 + n]); }
    for (int i = gtid; i < 128 * 128; i += gstr) { int n = i / 128, k = i % 128; P.BTnn[i]  = (short)f2bf(P.W_nn [(size_t)k * 128 + n]); }
    for (int i = gtid; i < 128 * 384; i += gstr) { int n = i / 384, k = i % 384; P.BTg1[i]  = (short)f2bf(P.W_g1 [(size_t)k * 128 + n]); }
    for (int i = gtid; i < 256 * 256; i += gstr) { int n = i >> 8, k = i & 255; float v = (k < 128) ? P.W_ih[n * 128 + k] : P.W_hh[n * 128 + (k - 128)]; P.BTcomb[i] = (short)f2bf(v); }
    for (int i = gtid; i < 128 * 128; i += gstr) { P.BTihn[i] = (short)f2bf(P.W_ih[256 * 128 + i]); P.BThhn[i] = (short)f2bf(P.W_hh[256 * 128 + i]); }
    grid.sync();

    // ---- P1: tie classification + compaction ----
    {
        int fmt = P.counters[0];
        for (int e = gtid; e < N_EDGES; e += gstr) {
            bool t = fmt ? (((const uint8_t*)P.tie_raw)[e] != 0)
                         : (((const int*)P.tie_raw)[e] != 0);
            if (t) {
                int r = P.ei[e], c = P.ei[N_EDGES + e];
                atomicAdd(&P.cpl_cnt[r], 1.f);
                atomicAdd(&P.cpl_cnt[c], 1.f);
                int idx = atomicAdd(&P.counters[1], 1);
                if (idx < TIE_CAP) { P.tie_list[idx] = e; P.tie_row[idx] = r; P.tie_col[idx] = c; }
            }
        }
    }
    grid.sync();

    // ---- P2: edge weights ----
    {
        int fmt = P.counters[0];
        for (int e = gtid; e < N_EDGES; e += gstr) {
            bool t = fmt ? (((const uint8_t*)P.tie_raw)[e] != 0)
                         : (((const int*)P.tie_raw)[e] != 0);
            float w = 0.f;
            if (!t) {
                int c = P.ei[N_EDGES + e];
                if (P.cpl_cnt[c] > 0.f) {
                    float X = fabsf(P.attr[(size_t)e * 10 + 1]);
                    w = 1.f / sqrtf(X * X + 1e-6f);
                    atomicAdd(&P.w_den[c], w);
                    atomicAdd(&P.hist[c], 1);
                }
            }
            P.w_arr[e] = w;
        }
    }
    grid.sync();

    // ---- P3: wnorm + deg/sumw + scan1 ----
    for (int e = gtid; e < N_EDGES; e += gstr) {
        float w = P.w_arr[e];
        if (w != 0.f) P.w_arr[e] = w / (P.w_den[P.ei[N_EDGES + e]] + 1e-6f);
    }
    for (int n = gtid; n < N_NODES; n += gstr) {
        P.deg_inv[n] = 1.f / fmaxf(P.cpl_cnt[n], 1.f);
        float wd = P.w_den[n];
        P.sumw[n] = wd / (wd + 1e-6f);
    }
    const int NCH = (N_NODES + 511) / 512;   // 98
    for (int vb = bid; vb < NCH; vb += nb) {
        int i = vb * 512 + tid;
        int v = (i < N_NODES) ? P.hist[i] : 0;
        scan_s[tid] = v;
        __syncthreads();
        for (int o = 1; o < 512; o <<= 1) {
            int u = (tid >= o) ? scan_s[tid - o] : 0;
            __syncthreads();
            scan_s[tid] += u;
            __syncthreads();
        }
        if (i < N_NODES) P.excl[i] = scan_s[tid] - v;
        if (tid == 511) P.bsum[vb] = scan_s[tid];
        __syncthreads();
    }
    grid.sync();

    // ---- P4: serial block-sum scan ----
    if (bid == 0 && tid == 0) {
        int run = 0;
        for (int b = 0; b < NCH; ++b) { int x = P.bsum[b]; P.bsum[b] = run; run += x; }
        P.counters[2] = run;
    }
    grid.sync();

    // ---- P5: row_ptr / cursor ----
    for (int i = gtid; i < N_NODES; i += gstr) {
        int v = P.excl[i] + P.bsum[i >> 9];
        P.row_ptr[i] = v;
        P.cursor[i] = v;
    }
    if (gtid == 0) P.row_ptr[N_NODES] = P.counters[2];
    grid.sync();

    // ---- P6: CSR fill ----
    for (int e = gtid; e < N_EDGES; e += gstr) {
        float w = P.w_arr[e];
        if (w != 0.f) {
            int c = P.ei[N_EDGES + e];
            int pos = atomicAdd(&P.cursor[c], 1);
            P.csr_row[pos] = P.ei[e];
            P.csr_w[pos] = w;
        }
    }
    grid.sync();

    // ---- iterations ----
    int cnt = P.counters[1]; if (cnt > TIE_CAP) cnt = TIE_CAP;
    const int ntt = (cnt + 127) / 128;
    const int ntn = (N_NODES + 127) / 128;

    for (int it = 0; it < NITER; ++it) {
        // P7a: tie tiles
        for (int t = bid; t < ntt; t += nb) {
            __syncthreads();
            tie_tile(P, t * 128, cnt, S0, S1, S2, tid, lane, wr, wc);
        }
        // P7b: m_node gather (no LDS; independent of tie phase)
        {
            int wv = bid * 8 + wid;
            for (int n = wv; n < N_NODES; n += nb * 8) {
                int s = P.row_ptr[n], t2 = P.row_ptr[n + 1];
                float a0 = 0.f, a1 = 0.f;
                for (int j = s; j < t2; ++j) {
                    int r = P.csr_row[j];
                    float w = P.csr_w[j];
                    uint32_t v = *(const uint32_t*)(P.h_bf + (size_t)r * HDIM + lane * 2);
                    a0 += w * bf2f(v & 0xffffu);
                    a1 += w * bf2f(v >> 16);
                }
                *(uint32_t*)(P.agg + (size_t)n * HDIM + lane * 2) =
                    f2bf(a0) | (f2bf(a1) << 16);
            }
        }
        grid.sync();
        // P8: mega tiles (self-zero m_edge for next iter)
        for (int t = bid; t < ntn; t += nb) {
            __syncthreads();
            mega_tile(P, t * 128, S0, S1, S2, S3, g_red, g_fin, sw_s,
                      tid, lane, wr, wc);
        }
        grid.sync();
    }
}

// ---------------- launch ----------------
extern "C" void kernel_launch(void* const* d_in, const int* in_sizes, int n_in,
                              void* d_out, int out_size, void* d_ws, size_t ws_size,
                              hipStream_t stream)
{
    Params P;
    P.h     = (const float*)d_in[0];
    P.e     = (const float*)d_in[1];
    P.attr  = (const float*)d_in[2];
    P.W_er1 = (const float*)d_in[3];
    P.b_er1 = (const float*)d_in[4];
    P.W_er2 = (const float*)d_in[5];
    P.b_er2 = (const float*)d_in[6];
    P.W_ih  = (const float*)d_in[7];
    P.W_hh  = (const float*)d_in[8];
    P.b_ih  = (const float*)d_in[9];
    P.b_hh  = (const float*)d_in[10];
    P.W_nn  = (const float*)d_in[11];
    P.b_nn  = (const float*)d_in[12];
    P.W_g1  = (const float*)d_in[13];
    P.b_g1  = (const float*)d_in[14];
    P.W_g2  = (const float*)d_in[15];
    P.b_g2  = (const float*)d_in[16];
    P.ei    = (const int*)d_in[17];
    P.tie_raw = d_in[18];

    P.out_h = (float*)d_out;
    P.out_e = P.out_h + (size_t)N_NODES * HDIM;

    char* ws = (char*)d_ws;
    size_t off = 0;
    auto alloc = [&](size_t bytes) -> void* {
        void* p = ws + off;
        off = (off + bytes + 255) & ~(size_t)255;
        return p;
    };
    P.cpl_cnt = (float*)alloc((size_t)N_NODES * 4);
    P.w_den   = (float*)alloc((size_t)N_NODES * 4);
    P.hist    = (int*)  alloc((size_t)N_NODES * 4);
    P.counters= (int*)  alloc(256);
    P.deg_inv = (float*)alloc((size_t)N_NODES * 4);
    P.sumw    = (float*)alloc((size_t)N_NODES * 4);
    P.w_arr   = (float*)alloc((size_t)N_EDGES * 4);
    P.tie_list= (int*)alloc((size_t)TIE_CAP * 4);
    P.tie_row = (int*)alloc((size_t)TIE_CAP * 4);
    P.tie_col = (int*)alloc((size_t)TIE_CAP * 4);
    P.BTer1   = (short*)alloc((size_t)256 * 384 * 2);
    P.BTer2   = (short*)alloc((size_t)128 * 256 * 2);
    P.BTnn    = (short*)alloc((size_t)128 * 128 * 2);
    P.BTg1    = (short*)alloc((size_t)128 * 384 * 2);
    P.BTcomb  = (short*)alloc((size_t)256 * 256 * 2);
    P.BTihn   = (short*)alloc((size_t)128 * 128 * 2);
    P.BThhn   = (short*)alloc((size_t)128 * 128 * 2);
    P.h_bf    = (uint16_t*)alloc((size_t)N_NODES * HDIM * 2);
    P.agg     = (uint16_t*)alloc((size_t)N_NODES * HDIM * 2);
    P.m_edge  = (float*)alloc((size_t)N_NODES * HDIM * 4);
    P.excl    = (int*)alloc((size_t)N_NODES * 4);
    P.bsum    = (int*)alloc(256 * 4);
    P.row_ptr = (int*)alloc((size_t)(N_NODES + 1) * 4);
    P.cursor  = (int*)alloc((size_t)N_NODES * 4);
    P.csr_row = (int*)alloc((size_t)N_EDGES * 4);
    P.csr_w   = (float*)alloc((size_t)N_EDGES * 4);
    if (off > ws_size) return;

    void* args[] = { &P };
    hipLaunchCooperativeKernel((void*)k_mono, dim3(256), dim3(512), args, 0, stream);
}

// Round 7
// 1240.729 us; speedup vs baseline: 1.2777x; 1.2777x over previous
//
#include <hip/hip_runtime.h>
#include <cstdint>

#define N_NODES 50000
#define N_EDGES 800000
#define HDIM    128
#define TIE_CAP 44000
#define NITER   2
#define SCAN_B  256

typedef __attribute__((ext_vector_type(8))) short bf16x8;
typedef __attribute__((ext_vector_type(4))) float f32x4;

struct Params {
    const float *h, *e, *attr;
    const float *W_er1, *b_er1, *W_er2, *b_er2;
    const float *W_ih, *W_hh, *b_ih, *b_hh;
    const float *W_nn, *b_nn, *W_g1, *b_g1, *W_g2, *b_g2;
    const int* ei; const void* tie_raw;
    float *out_h, *out_e;
    float *cpl_cnt, *w_den, *deg_inv, *sumw, *w_arr, *m_edge, *csr_w;
    int *hist, *counters, *tie_list, *tie_row, *tie_col;
    int *excl, *bsum, *row_ptr, *cursor, *csr_row;
    short *BTer1, *BTer2, *BTnn, *BTg1, *BTcomb, *BTihn, *BThhn;
    uint16_t *h_bf, *agg;
};

__device__ __forceinline__ uint32_t f2bf(float f) {
    uint32_t u = __builtin_bit_cast(uint32_t, f);
    return (u + 0x7fffu + ((u >> 16) & 1u)) >> 16;   // RNE
}
__device__ __forceinline__ float bf2f(uint32_t b) {
    return __builtin_bit_cast(float, b << 16);
}
__device__ __forceinline__ uint32_t comb2(uint32_t me, uint32_t mn, float g) {
    float a0 = bf2f(me & 0xffffu) + g * bf2f(mn & 0xffffu);
    float a1 = bf2f(me >> 16)     + g * bf2f(mn >> 16);
    return f2bf(a0) | (f2bf(a1) << 16);
}

// ---- 64-row LDS tiles: [64 rows][128 bf16] = 256B rows, byte ^= (row&7)<<4 ----
// 256 threads stage; 4 waves compute (wave wc covers cols h*64 + wc*16 + lane&15)

__device__ __forceinline__ void stage_a64(const float* base, const int* gidx,
                                          int m0, int Mlim, char* tile, int tid)
{
    const int c = tid & 15;
    #pragma unroll
    for (int p = 0; p < 4; ++p) {
        int row = p * 16 + (tid >> 4);
        int ar = m0 + row; if (ar >= Mlim) ar = Mlim - 1;
        long g = gidx ? gidx[ar] : ar;
        const float* s = base + g * HDIM + c * 4;
        float4 v0 = *(const float4*)s;
        float4 v1 = *(const float4*)(s + 64);
        uint2 w0 = make_uint2(f2bf(v0.x) | (f2bf(v0.y) << 16),
                              f2bf(v0.z) | (f2bf(v0.w) << 16));
        uint2 w1 = make_uint2(f2bf(v1.x) | (f2bf(v1.y) << 16),
                              f2bf(v1.z) | (f2bf(v1.w) << 16));
        int sw = (row & 7) << 4;
        *(uint2*)(tile + row * 256 + ((c * 8) ^ sw)) = w0;
        *(uint2*)(tile + row * 256 + ((c * 8 + 128) ^ sw)) = w1;
    }
}

__device__ __forceinline__ void stage_abf64(const uint16_t* base, const int* gidx,
                                            int m0, int Mlim, char* tile, int tid)
{
    const int c = tid & 15;
    #pragma unroll
    for (int p = 0; p < 4; ++p) {
        int row = p * 16 + (tid >> 4);
        int ar = m0 + row; if (ar >= Mlim) ar = Mlim - 1;
        long g = gidx ? gidx[ar] : ar;
        uint4 v = *(const uint4*)(base + g * HDIM + c * 8);
        *(uint4*)(tile + row * 256 + ((c * 16) ^ ((row & 7) << 4))) = v;
    }
}

// stage 64 n-rows x 128 k from bf16 [N][ldk]
__device__ __forceinline__ void stage_b64(const short* BT, int ldk,
                                          int n0, int k0, char* tile, int tid)
{
    const int c = tid & 15;
    #pragma unroll
    for (int p = 0; p < 4; ++p) {
        int n = p * 16 + (tid >> 4);
        uint4 v = *(const uint4*)&BT[(size_t)(n0 + n) * ldk + k0 + c * 8];
        *(uint4*)(tile + n * 256 + ((c * 16) ^ ((n & 7) << 4))) = v;
    }
}

// one K=128 chunk x one 64-col n-half; acc[mi] (wave covers 16 cols of the half)
__device__ __forceinline__ void mfma64(const char* At, const char* Bt,
                                       int wc, int lane, f32x4* acc)
{
    #pragma unroll
    for (int ks = 0; ks < 4; ++ks) {
        int kb = ks * 64 + (lane >> 4) * 16;
        int n = wc * 16 + (lane & 15);
        bf16x8 bF = *(const bf16x8*)(Bt + n * 256 + (kb ^ ((n & 7) << 4)));
        #pragma unroll
        for (int mi = 0; mi < 4; ++mi) {
            int row = mi * 16 + (lane & 15);
            bf16x8 aF = *(const bf16x8*)(At + row * 256 + (kb ^ ((row & 7) << 4)));
            acc[mi] = __builtin_amdgcn_mfma_f32_16x16x32_bf16(aF, bF, acc[mi], 0, 0, 0);
        }
    }
}

// ---------------- fused tie-edge kernel (48 KB LDS -> 3 blocks/CU) ----------
__global__ __launch_bounds__(256, 2)
void k_tie_fused(Params P)
{
    int cnt = P.counters[1]; if (cnt > TIE_CAP) cnt = TIE_CAP;
    const int m0 = blockIdx.x * 64;
    if (cnt == 0 || m0 >= cnt) return;

    __shared__ __align__(16) char At[16 * 1024];
    __shared__ __align__(16) char Ct[16 * 1024];
    __shared__ __align__(16) char Bt[16 * 1024];

    const int tid = threadIdx.x, lane = tid & 63, wc = tid >> 6;
    const int l = lane & 15, rg = (lane >> 4) << 2;

    // L1: [e|h_row|h_col](K=384) @ W_er1 -> N=256 in 4 quarters
    f32x4 acc1[4][4] = {};   // [q][mi]
    #pragma unroll 1
    for (int c3 = 0; c3 < 3; ++c3) {
        if (c3 == 0) stage_a64(P.out_e, P.tie_list, m0, cnt, At, tid);
        else         stage_abf64(P.h_bf, (c3 == 1) ? P.tie_row : P.tie_col, m0, cnt, At, tid);
        #pragma unroll 1
        for (int q = 0; q < 4; ++q) {
            stage_b64(P.BTer1, 384, q * 64, c3 * 128, Bt, tid);
            __syncthreads();
            mfma64(At, Bt, wc, lane, acc1[q]);
            __syncthreads();
        }
    }

    // C1 = relu(acc1 + b_er1) -> bf16 into At (k 0-127) / Ct (k 128-255)
    #pragma unroll
    for (int q = 0; q < 4; ++q) {
        int col = q * 64 + wc * 16 + l;
        float bv = P.b_er1[col];
        char* T = (q < 2) ? At : Ct;
        int cl = col & 127;
        #pragma unroll
        for (int mi = 0; mi < 4; ++mi)
            #pragma unroll
            for (int j = 0; j < 4; ++j) {
                int row = mi * 16 + rg + j;
                float v = fmaxf(acc1[q][mi][j] + bv, 0.f);
                *(uint16_t*)(T + row * 256 + ((cl * 2) ^ ((row & 7) << 4))) =
                    (uint16_t)f2bf(v);
            }
    }
    __syncthreads();

    // L2: C1(K=256) @ W_er2 -> N=128
    f32x4 acc2[2][4] = {};   // [h][mi]
    #pragma unroll 1
    for (int c2 = 0; c2 < 2; ++c2) {
        #pragma unroll 1
        for (int hh = 0; hh < 2; ++hh) {
            stage_b64(P.BTer2, 256, hh * 64, c2 * 128, Bt, tid);
            __syncthreads();
            mfma64(c2 ? Ct : At, Bt, wc, lane, acc2[hh]);
            __syncthreads();
        }
    }

    // epilogue: e_work += eref; scatter v*deg_inv to m_edge
    #pragma unroll
    for (int mi = 0; mi < 4; ++mi)
        #pragma unroll
        for (int j = 0; j < 4; ++j) {
            int i = m0 + mi * 16 + rg + j;
            if (i < cnt) {
                int e = P.tie_list[i], r = P.tie_row[i], cc = P.tie_col[i];
                float dr = P.deg_inv[r], dc = P.deg_inv[cc];
                #pragma unroll
                for (int hh = 0; hh < 2; ++hh) {
                    int col = hh * 64 + wc * 16 + l;
                    float er = acc2[hh][mi][j] + P.b_er2[col];
                    size_t eb = (size_t)e * HDIM + col;
                    float v = P.out_e[eb] + er;
                    P.out_e[eb] = v;
                    atomicAdd(&P.m_edge[(size_t)r * HDIM + col], v * dr);
                    atomicAdd(&P.m_edge[(size_t)cc * HDIM + col], v * dc);
                }
            }
        }
}

// ---------------- mega node kernel (~65 KB LDS -> 2 blocks/CU) --------------
__global__ __launch_bounds__(256, 2)
void k_mega(Params P)
{
    const int m0 = blockIdx.x * 64;
    __shared__ __align__(16) char Tme[16 * 1024];
    __shared__ __align__(16) char Tmn[16 * 1024];   // agg -> m_node -> M
    __shared__ __align__(16) char Th [16 * 1024];
    __shared__ __align__(16) char Bt [16 * 1024];
    __shared__ float g_red[4][64];
    __shared__ float g_fin[64];

    const int tid = threadIdx.x, lane = tid & 63, wc = tid >> 6;
    const int l = lane & 15, rg = (lane >> 4) << 2;

    stage_a64(P.m_edge, nullptr, m0, N_NODES, Tme, tid);
    stage_abf64(P.agg,  nullptr, m0, N_NODES, Tmn, tid);
    stage_abf64(P.h_bf, nullptr, m0, N_NODES, Th,  tid);

    // phase0: m_node = agg @ W_nn + sumw*b_nn
    f32x4 accM[2][4] = {};
    stage_b64(P.BTnn, 128, 0, 0, Bt, tid);
    __syncthreads();
    // self-zero own m_edge rows for the NEXT iteration (Tme staged above)
    {
        int lim = (N_NODES - m0 < 64 ? N_NODES - m0 : 64) * HDIM / 4;
        float4* mp = (float4*)(P.m_edge + (size_t)m0 * HDIM);
        for (int i2 = tid; i2 < lim; i2 += 256)
            mp[i2] = make_float4(0.f, 0.f, 0.f, 0.f);
    }
    mfma64(Tmn, Bt, wc, lane, accM[0]);
    __syncthreads();
    stage_b64(P.BTnn, 128, 64, 0, Bt, tid);
    __syncthreads();
    mfma64(Tmn, Bt, wc, lane, accM[1]);
    __syncthreads();
    #pragma unroll
    for (int hh = 0; hh < 2; ++hh) {
        int col = hh * 64 + wc * 16 + l;
        float bv = P.b_nn[col];
        #pragma unroll
        for (int mi = 0; mi < 4; ++mi)
            #pragma unroll
            for (int j = 0; j < 4; ++j) {
                int row = mi * 16 + rg + j;
                int node = m0 + row; if (node >= N_NODES) node = N_NODES - 1;
                float v = accM[hh][mi][j] + P.sumw[node] * bv;
                *(uint16_t*)(Tmn + row * 256 + ((col * 2) ^ ((row & 7) << 4))) =
                    (uint16_t)f2bf(v);
            }
    }
    __syncthreads();

    // gate: [me|mn|h](K=384) @ W_g1
    f32x4 accG[2][4] = {};
    #pragma unroll 1
    for (int c3 = 0; c3 < 3; ++c3) {
        const char* Ax = (c3 == 0) ? Tme : (c3 == 1) ? Tmn : Th;
        #pragma unroll 1
        for (int hh = 0; hh < 2; ++hh) {
            stage_b64(P.BTg1, 384, hh * 64, c3 * 128, Bt, tid);
            __syncthreads();
            mfma64(Ax, Bt, wc, lane, accG[hh]);
            __syncthreads();
        }
    }
    #pragma unroll
    for (int mi = 0; mi < 4; ++mi)
        #pragma unroll
        for (int j = 0; j < 4; ++j) {
            float p = 0.f;
            #pragma unroll
            for (int hh = 0; hh < 2; ++hh) {
                int col = hh * 64 + wc * 16 + l;
                p += fmaxf(accG[hh][mi][j] + P.b_g1[col], 0.f) * P.W_g2[col];
            }
            #pragma unroll
            for (int o = 8; o; o >>= 1) p += __shfl_xor(p, o);
            if (l == 0) g_red[wc][mi * 16 + rg + j] = p;
        }
    __syncthreads();
    if (tid < 64) {
        float t = g_red[0][tid] + g_red[1][tid] + g_red[2][tid] + g_red[3][tid]
                + P.b_g2[0];
        g_fin[tid] = 1.f / (1.f + __expf(-t));
    }
    __syncthreads();

    // M = me + g*mn (bf16, in place of Tmn)
    {
        const int c = tid & 15;
        #pragma unroll
        for (int p2 = 0; p2 < 4; ++p2) {
            int row = p2 * 16 + (tid >> 4);
            float g = g_fin[row];
            int sw = (row & 7) << 4;
            #pragma unroll
            for (int hh = 0; hh < 2; ++hh) {
                int off = (c * 8 + hh * 128) ^ sw;
                uint2 me2 = *(uint2*)(Tme + row * 256 + off);
                uint2 mn2 = *(uint2*)(Tmn + row * 256 + off);
                *(uint2*)(Tmn + row * 256 + off) =
                    make_uint2(comb2(me2.x, mn2.x, g), comb2(me2.y, mn2.y, g));
            }
        }
    }
    __syncthreads();

    // GRU: r,z via [M|h]@BTcomb (K=256); gi_n/gh_n (K=128)
    f32x4 aR[2][4] = {}, aZ[2][4] = {}, aGI[2][4] = {}, aGH[2][4] = {};
    #pragma unroll 1
    for (int ac = 0; ac < 2; ++ac) {
        const char* Ax = ac ? Th : Tmn;
        #pragma unroll 1
        for (int hh = 0; hh < 2; ++hh) {
            stage_b64(P.BTcomb, 256, hh * 64, ac * 128, Bt, tid);
            __syncthreads();
            mfma64(Ax, Bt, wc, lane, aR[hh]);
            __syncthreads();
        }
    }
    #pragma unroll 1
    for (int ac = 0; ac < 2; ++ac) {
        const char* Ax = ac ? Th : Tmn;
        #pragma unroll 1
        for (int hh = 0; hh < 2; ++hh) {
            stage_b64(P.BTcomb, 256, 128 + hh * 64, ac * 128, Bt, tid);
            __syncthreads();
            mfma64(Ax, Bt, wc, lane, aZ[hh]);
            __syncthreads();
        }
    }
    #pragma unroll 1
    for (int hh = 0; hh < 2; ++hh) {
        stage_b64(P.BTihn, 128, hh * 64, 0, Bt, tid);
        __syncthreads();
        mfma64(Tmn, Bt, wc, lane, aGI[hh]);
        __syncthreads();
    }
    #pragma unroll 1
    for (int hh = 0; hh < 2; ++hh) {
        stage_b64(P.BThhn, 128, hh * 64, 0, Bt, tid);
        __syncthreads();
        mfma64(Th, Bt, wc, lane, aGH[hh]);
        __syncthreads();
    }

    // GRU epilogue (masked); maintains h_bf shadow
    #pragma unroll
    for (int hh = 0; hh < 2; ++hh) {
        int col = hh * 64 + wc * 16 + l;
        float br  = P.b_ih[col] + P.b_hh[col];
        float bz  = P.b_ih[128 + col] + P.b_hh[128 + col];
        float bin = P.b_ih[256 + col], bhn = P.b_hh[256 + col];
        #pragma unroll
        for (int mi = 0; mi < 4; ++mi)
            #pragma unroll
            for (int j = 0; j < 4; ++j) {
                int node = m0 + mi * 16 + rg + j;
                if (node < N_NODES && P.cpl_cnt[node] > 0.f) {
                    float r = 1.f / (1.f + __expf(-(aR[hh][mi][j] + br)));
                    float z = 1.f / (1.f + __expf(-(aZ[hh][mi][j] + bz)));
                    float nn = tanhf(aGI[hh][mi][j] + bin + r * (aGH[hh][mi][j] + bhn));
                    size_t hb = (size_t)node * HDIM + col;
                    float hv = P.out_h[hb];
                    float hn = (1.f - z) * nn + z * hv;
                    P.out_h[hb] = hn;
                    P.h_bf[hb] = (uint16_t)f2bf(hn);
                }
            }
    }
}

// ---------------- gather: agg[n] = sum w_norm * h_bf[row] ----------------
__global__ __launch_bounds__(256)
void k_gather(Params P)
{
    int n = blockIdx.x * 4 + (threadIdx.x >> 6);
    if (n >= N_NODES) return;
    int lane = threadIdx.x & 63;
    int s = P.row_ptr[n], t = P.row_ptr[n + 1];
    float a0 = 0.f, a1 = 0.f;
    for (int j = s; j < t; ++j) {
        int r = P.csr_row[j];
        float w = P.csr_w[j];
        uint32_t v = *(const uint32_t*)(P.h_bf + (size_t)r * HDIM + lane * 2);
        a0 += w * bf2f(v & 0xffffu);
        a1 += w * bf2f(v >> 16);
    }
    *(uint32_t*)(P.agg + (size_t)n * HDIM + lane * 2) = f2bf(a0) | (f2bf(a1) << 16);
}

// ---------------- k_prep: detect + copies + zeroing + weight prep -----------
__global__ __launch_bounds__(256)
void k_prep(Params P)
{
    const int gtid = blockIdx.x * 256 + threadIdx.x;
    const int gstr = gridDim.x * 256;
    if (blockIdx.x == 0 && threadIdx.x < 64) {
        const uint8_t* tr = (const uint8_t*)P.tie_raw;
        int cdet = 0;
        for (int i = threadIdx.x; i < 4096; i += 64)
            if ((i & 3) && tr[i]) cdet = 1;
        unsigned long long mm = __ballot(cdet != 0);
        if (threadIdx.x == 0) {
            P.counters[0] = (mm != 0ull) ? 1 : 0;
            P.counters[1] = 0; P.counters[2] = 0;
        }
    }
    for (int i = gtid; i < N_NODES * HDIM / 4; i += gstr) {
        float4 v = ((const float4*)P.h)[i];
        ((float4*)P.out_h)[i] = v;
        *(uint2*)(P.h_bf + (size_t)i * 4) =
            make_uint2(f2bf(v.x) | (f2bf(v.y) << 16), f2bf(v.z) | (f2bf(v.w) << 16));
    }
    for (int i = gtid; i < N_NODES * HDIM / 4; i += gstr)
        ((float4*)P.m_edge)[i] = make_float4(0.f, 0.f, 0.f, 0.f);
    for (int i = gtid; i < N_NODES; i += gstr) {
        P.cpl_cnt[i] = 0.f; P.w_den[i] = 0.f; P.hist[i] = 0;
    }
    for (int i = gtid; i < 384 * 256; i += gstr) { int n = i / 384, k = i % 384; P.BTer1[i] = (short)f2bf(P.W_er1[(size_t)k * 256 + n]); }
    for (int i = gtid; i < 128 * 256; i += gstr) { int n = i / 256, k = i % 256; P.BTer2[i] = (short)f2bf(P.W_er2[(size_t)k * 128 + n]); }
    for (int i = gtid; i < 128 * 128; i += gstr) { int n = i / 128, k = i % 128; P.BTnn[i]  = (short)f2bf(P.W_nn [(size_t)k * 128 + n]); }
    for (int i = gtid; i < 128 * 384; i += gstr) { int n = i / 384, k = i % 384; P.BTg1[i]  = (short)f2bf(P.W_g1 [(size_t)k * 128 + n]); }
    for (int i = gtid; i < 256 * 256; i += gstr) { int n = i >> 8, k = i & 255; float v = (k < 128) ? P.W_ih[n * 128 + k] : P.W_hh[n * 128 + (k - 128)]; P.BTcomb[i] = (short)f2bf(v); }
    for (int i = gtid; i < 128 * 128; i += gstr) { P.BTihn[i] = (short)f2bf(P.W_ih[256 * 128 + i]); P.BThhn[i] = (short)f2bf(P.W_hh[256 * 128 + i]); }
}

// ---------------- tie classification (wave-aggregated compaction) -----------
__global__ __launch_bounds__(256)
void k_tie(Params P)
{
    int e = blockIdx.x * 256 + threadIdx.x;
    int fmt = P.counters[0];
    bool t = false; int r = 0, c = 0;
    if (e < N_EDGES)
        t = fmt ? (((const uint8_t*)P.tie_raw)[e] != 0)
                : (((const int*)P.tie_raw)[e] != 0);
    if (t) {
        r = P.ei[e]; c = P.ei[N_EDGES + e];
        atomicAdd(&P.cpl_cnt[r], 1.f);
        atomicAdd(&P.cpl_cnt[c], 1.f);
    }
    unsigned long long m = __ballot(t);
    if (m == 0ull) return;
    int lane = threadIdx.x & 63;
    int first = __ffsll((unsigned long long)m) - 1;
    int base = 0;
    if (lane == first) base = atomicAdd(&P.counters[1], __popcll(m));
    base = __shfl(base, first);
    if (t) {
        int idx = base + __popcll(m & ((1ull << lane) - 1ull));
        if (idx < TIE_CAP) {
            P.tie_list[idx] = e; P.tie_row[idx] = r; P.tie_col[idx] = c;
        }
    }
}

__global__ __launch_bounds__(256)
void k_w(Params P)
{
    int e = blockIdx.x * 256 + threadIdx.x;
    if (e >= N_EDGES) return;
    int fmt = P.counters[0];
    bool t = fmt ? (((const uint8_t*)P.tie_raw)[e] != 0)
                 : (((const int*)P.tie_raw)[e] != 0);
    float w = 0.f;
    if (!t) {
        int c = P.ei[N_EDGES + e];
        if (P.cpl_cnt[c] > 0.f) {
            float X = fabsf(P.attr[(size_t)e * 10 + 1]);
            w = 1.f / sqrtf(X * X + 1e-6f);
            atomicAdd(&P.w_den[c], w);
            atomicAdd(&P.hist[c], 1);
        }
    }
    P.w_arr[e] = w;
}

// ---------------- CSR build ----------------
__global__ __launch_bounds__(SCAN_B)
void k_scan1(Params P)
{
    __shared__ int s[SCAN_B];
    int t = threadIdx.x;
    int i = blockIdx.x * SCAN_B + t;
    int v = (i < N_NODES) ? P.hist[i] : 0;
    s[t] = v;
    __syncthreads();
    for (int o = 1; o < SCAN_B; o <<= 1) {
        int u = (t >= o) ? s[t - o] : 0;
        __syncthreads();
        s[t] += u;
        __syncthreads();
    }
    if (i < N_NODES) P.excl[i] = s[t] - v;
    if (t == SCAN_B - 1) P.bsum[blockIdx.x] = s[t];
}

__global__ void k_scan2(Params P)
{
    const int NB = (N_NODES + SCAN_B - 1) / SCAN_B;
    if (threadIdx.x == 0) {
        int run = 0;
        for (int b = 0; b < NB; ++b) { int x = P.bsum[b]; P.bsum[b] = run; run += x; }
        P.counters[2] = run;
    }
}

__global__ __launch_bounds__(256)
void k_scan3(Params P)   // + deg_inv/sumw fused
{
    int i = blockIdx.x * 256 + threadIdx.x;
    if (i < N_NODES) {
        int v = P.excl[i] + P.bsum[i >> 8];
        P.row_ptr[i] = v;
        P.cursor[i] = v;
        P.deg_inv[i] = 1.f / fmaxf(P.cpl_cnt[i], 1.f);
        float wd = P.w_den[i];
        P.sumw[i] = wd / (wd + 1e-6f);
    }
    if (i == N_NODES) P.row_ptr[N_NODES] = P.counters[2];
}

__global__ __launch_bounds__(256)
void k_fill(Params P)   // + w-normalization fused
{
    int e = blockIdx.x * 256 + threadIdx.x;
    if (e >= N_EDGES) return;
    float w = P.w_arr[e];
    if (w == 0.f) return;
    int c = P.ei[N_EDGES + e];
    int pos = atomicAdd(&P.cursor[c], 1);
    P.csr_row[pos] = P.ei[e];
    P.csr_w[pos] = w / (P.w_den[c] + 1e-6f);
}

// ---------------- launch ----------------
extern "C" void kernel_launch(void* const* d_in, const int* in_sizes, int n_in,
                              void* d_out, int out_size, void* d_ws, size_t ws_size,
                              hipStream_t stream)
{
    Params P;
    P.h     = (const float*)d_in[0];
    P.e     = (const float*)d_in[1];
    P.attr  = (const float*)d_in[2];
    P.W_er1 = (const float*)d_in[3];
    P.b_er1 = (const float*)d_in[4];
    P.W_er2 = (const float*)d_in[5];
    P.b_er2 = (const float*)d_in[6];
    P.W_ih  = (const float*)d_in[7];
    P.W_hh  = (const float*)d_in[8];
    P.b_ih  = (const float*)d_in[9];
    P.b_hh  = (const float*)d_in[10];
    P.W_nn  = (const float*)d_in[11];
    P.b_nn  = (const float*)d_in[12];
    P.W_g1  = (const float*)d_in[13];
    P.b_g1  = (const float*)d_in[14];
    P.W_g2  = (const float*)d_in[15];
    P.b_g2  = (const float*)d_in[16];
    P.ei    = (const int*)d_in[17];
    P.tie_raw = d_in[18];

    P.out_h = (float*)d_out;
    P.out_e = P.out_h + (size_t)N_NODES * HDIM;

    char* ws = (char*)d_ws;
    size_t off = 0;
    auto alloc = [&](size_t bytes) -> void* {
        void* p = ws + off;
        off = (off + bytes + 255) & ~(size_t)255;
        return p;
    };
    P.cpl_cnt = (float*)alloc((size_t)N_NODES * 4);
    P.w_den   = (float*)alloc((size_t)N_NODES * 4);
    P.hist    = (int*)  alloc((size_t)N_NODES * 4);
    P.counters= (int*)  alloc(256);
    P.deg_inv = (float*)alloc((size_t)N_NODES * 4);
    P.sumw    = (float*)alloc((size_t)N_NODES * 4);
    P.w_arr   = (float*)alloc((size_t)N_EDGES * 4);
    P.tie_list= (int*)alloc((size_t)TIE_CAP * 4);
    P.tie_row = (int*)alloc((size_t)TIE_CAP * 4);
    P.tie_col = (int*)alloc((size_t)TIE_CAP * 4);
    P.BTer1   = (short*)alloc((size_t)256 * 384 * 2);
    P.BTer2   = (short*)alloc((size_t)128 * 256 * 2);
    P.BTnn    = (short*)alloc((size_t)128 * 128 * 2);
    P.BTg1    = (short*)alloc((size_t)128 * 384 * 2);
    P.BTcomb  = (short*)alloc((size_t)256 * 256 * 2);
    P.BTihn   = (short*)alloc((size_t)128 * 128 * 2);
    P.BThhn   = (short*)alloc((size_t)128 * 128 * 2);
    P.h_bf    = (uint16_t*)alloc((size_t)N_NODES * HDIM * 2);
    P.agg     = (uint16_t*)alloc((size_t)N_NODES * HDIM * 2);
    P.m_edge  = (float*)alloc((size_t)N_NODES * HDIM * 4);
    P.excl    = (int*)alloc((size_t)N_NODES * 4);
    P.bsum    = (int*)alloc(256 * 4);
    P.row_ptr = (int*)alloc((size_t)(N_NODES + 1) * 4);
    P.cursor  = (int*)alloc((size_t)N_NODES * 4);
    P.csr_row = (int*)alloc((size_t)N_EDGES * 4);
    P.csr_w   = (float*)alloc((size_t)N_EDGES * 4);
    if (off > ws_size) return;

    const int EB  = N_EDGES / 256;                    // 3125
    const int NB  = (N_NODES + SCAN_B - 1) / SCAN_B;  // 196
    const int GT  = TIE_CAP / 64;                     // 688
    const int GN  = (N_NODES + 63) / 64;              // 782

    k_prep<<<1024, 256, 0, stream>>>(P);
    hipMemcpyAsync(P.out_e, P.e, (size_t)N_EDGES * HDIM * 4,
                   hipMemcpyDeviceToDevice, stream);
    k_tie<<<EB, 256, 0, stream>>>(P);
    k_w<<<EB, 256, 0, stream>>>(P);
    k_scan1<<<NB, SCAN_B, 0, stream>>>(P);
    k_scan2<<<1, 64, 0, stream>>>(P);
    k_scan3<<<NB, 256, 0, stream>>>(P);
    k_fill<<<EB, 256, 0, stream>>>(P);

    for (int it = 0; it < NITER; ++it) {
        k_tie_fused<<<GT, 256, 0, stream>>>(P);
        k_gather<<<(N_NODES + 3) / 4, 256, 0, stream>>>(P);
        k_mega<<<GN, 256, 0, stream>>>(P);
    }
}